// Round 6
// baseline (876.177 us; speedup 1.0000x reference)
//
#include <hip/hip_runtime.h>
#include <cstdint>
#include <cstddef>

// ---------------------------------------------------------------------------
// Llama decoder layer, MI355X.  B=1, T=2048, D=2048, FF=8192, NH=32, NKV=8,
// HD=64.  bf16 MFMA, fp32 accumulate.
// out = h2 + mlp(h2) + x0, where h2 = rms(h1 + attn(h1)), h1 = rms(x0).
//
// Round 6: flash_attn transpose-free rewrite.  S^T = K.Q^T puts P^T in the
// exact B-frag layout of mfma_f32_16x16x16bf16_1k (k = quad*4+j), so PV
// (O^T = V^T.P^T) runs straight from registers: no LDS P round-trip, no
// per-chunk fence, softmax reduces in-lane + 2 shfl steps (was 32 bpermutes).
// GEMM path unchanged from round 5 (BK=64 XOR-swizzle, split-K down-proj).
// ---------------------------------------------------------------------------

typedef __attribute__((ext_vector_type(8))) short short8;   // 8 x bf16
typedef __attribute__((ext_vector_type(4))) short s4b;      // 4 x bf16
typedef __attribute__((ext_vector_type(4))) float f32x4;

typedef __attribute__((address_space(1))) const void gvoid_t;  // global
typedef __attribute__((address_space(3))) void lvoid_t;        // LDS

__device__ inline unsigned short f2b(float f) {   // fp32 -> bf16 (RNE)
  unsigned int u = __float_as_uint(f);
  u += 0x7fffu + ((u >> 16) & 1u);
  return (unsigned short)(u >> 16);
}
__device__ inline float b2f(unsigned short s) {
  return __uint_as_float((unsigned int)s << 16);
}

// ---------------------------------------------------------------------------
// Cast + transpose:  W fp32 [R][ldW]  ->  Wt bf16 [ldW-cols][R]
// ---------------------------------------------------------------------------
__global__ __launch_bounds__(256) void transpose_cast(
    const float* __restrict__ W, unsigned short* __restrict__ Wt,
    int R, int ldW) {
  __shared__ unsigned short s[32 * 36];
  const int r0 = blockIdx.y * 32, c0 = blockIdx.x * 32;
  const int tr = threadIdx.x >> 3, tc = (threadIdx.x & 7) << 2;
  const float4 v = *(const float4*)(W + (size_t)(r0 + tr) * ldW + c0 + tc);
  s[tr * 36 + tc + 0] = f2b(v.x);
  s[tr * 36 + tc + 1] = f2b(v.y);
  s[tr * 36 + tc + 2] = f2b(v.z);
  s[tr * 36 + tc + 3] = f2b(v.w);
  __syncthreads();
  ushort4 o;
  o.x = s[(tc + 0) * 36 + tr];
  o.y = s[(tc + 1) * 36 + tr];
  o.z = s[(tc + 2) * 36 + tr];
  o.w = s[(tc + 3) * 36 + tr];
  *(ushort4*)(Wt + (size_t)(c0 + tr) * R + r0 + tc) = o;
}

// ---------------------------------------------------------------------------
// RMSNorm (one block per row of 2048) -> bf16.
// ---------------------------------------------------------------------------
__global__ __launch_bounds__(256) void rmsnorm(
    const float* __restrict__ X, const float* __restrict__ g,
    unsigned short* __restrict__ ob) {
  const int row = blockIdx.x;
  const float* x = X + (size_t)row * 2048;
  float ss = 0.f;
  for (int i = threadIdx.x; i < 2048; i += 256) { float v = x[i]; ss += v * v; }
  for (int off = 32; off; off >>= 1) ss += __shfl_down(ss, off, 64);
  __shared__ float red[4];
  if ((threadIdx.x & 63) == 0) red[threadIdx.x >> 6] = ss;
  __syncthreads();
  const float tot = red[0] + red[1] + red[2] + red[3];
  const float r = rsqrtf(tot * (1.f / 2048.f) + 1e-5f);
  for (int i = threadIdx.x; i < 2048; i += 256)
    ob[(size_t)row * 2048 + i] = f2b(x[i] * g[i] * r);
}

// ---------------------------------------------------------------------------
// out = x0 + b2f(h2), vectorized x4.  Pre-fill for the split-K down-proj.
// ---------------------------------------------------------------------------
__global__ __launch_bounds__(256) void add_res(
    const unsigned short* __restrict__ h2, const float* __restrict__ x,
    float* __restrict__ out) {
  const int i = blockIdx.x * 256 + threadIdx.x;
  const ushort4 h = ((const ushort4*)h2)[i];
  const float4 xv = ((const float4*)x)[i];
  float4 o;
  o.x = xv.x + b2f(h.x); o.y = xv.y + b2f(h.y);
  o.z = xv.z + b2f(h.z); o.w = xv.w + b2f(h.w);
  ((float4*)out)[i] = o;
}

// ---------------------------------------------------------------------------
// GEMM: acc[M][N] (+)= A[M][K] * Bt[N][K]^T   (bf16 in, fp32 acc)
// 128x128 tile, BK=64, XOR k-chunk swizzle, split-K via blockIdx.z.
// Epilogues: 1 wo+res, 3 silu*up, 4 plain bf16, 7 fused QKV, 8 atomicAdd.
// ---------------------------------------------------------------------------
__global__ __launch_bounds__(256, 2) void gemm_bt(
    const unsigned short* __restrict__ A, const unsigned short* __restrict__ Bt,
    float* Cf, unsigned short* Cb,
    const unsigned short* add1b, const float* add2,
    int N, int Kfull, int Kchunk, int epi, int Tld,
    unsigned short* Cb2, unsigned short* Cb3) {
  __shared__ unsigned short As[128 * 64];
  __shared__ unsigned short Bs[128 * 64];
  const int tid = threadIdx.x;
  const int wave = tid >> 6, lane = tid & 63;
  const int quad = lane >> 4, l16 = lane & 15;
  const int m0 = blockIdx.y * 128, n0 = blockIdx.x * 128;
  const int wr = (wave >> 1) * 64, wc = (wave & 1) * 64;
  const int Ks = blockIdx.z * Kchunk, Ke = Ks + Kchunk;

  f32x4 acc[4][4] = {};

  for (int k0 = Ks; k0 < Ke; k0 += 64) {
#pragma unroll
    for (int p = 0; p < 4; ++p) {
      const int idx = p * 256 + tid;
      const int row = idx >> 3;
      const int kc = ((idx & 7) ^ (row & 7)) * 8;
      const unsigned short* gA = A + (size_t)(m0 + row) * Kfull + k0 + kc;
      const unsigned short* gB = Bt + (size_t)(n0 + row) * Kfull + k0 + kc;
      unsigned short* lA = As + (size_t)(p * 256 + wave * 64) * 8;
      unsigned short* lB = Bs + (size_t)(p * 256 + wave * 64) * 8;
      __builtin_amdgcn_global_load_lds((gvoid_t*)gA, (lvoid_t*)lA, 16, 0, 0);
      __builtin_amdgcn_global_load_lds((gvoid_t*)gB, (lvoid_t*)lB, 16, 0, 0);
    }
    __syncthreads();

#pragma unroll
    for (int ks = 0; ks < 2; ++ks) {
      short8 af[4], bf[4];
#pragma unroll
      for (int i = 0; i < 4; ++i) {
        const int row = wr + i * 16 + l16;
        af[i] = *(const short8*)(As + row * 64 +
                                 (((ks << 2) | quad) ^ (row & 7)) * 8);
      }
#pragma unroll
      for (int j = 0; j < 4; ++j) {
        const int row = wc + j * 16 + l16;
        bf[j] = *(const short8*)(Bs + row * 64 +
                                 (((ks << 2) | quad) ^ (row & 7)) * 8);
      }
#pragma unroll
      for (int i = 0; i < 4; ++i)
#pragma unroll
        for (int j = 0; j < 4; ++j)
          acc[i][j] = __builtin_amdgcn_mfma_f32_16x16x32_bf16(
              af[i], bf[j], acc[i][j], 0, 0, 0);
    }
    __syncthreads();
  }

  // C/D layout: col = lane&15, row = quad*4 + reg.
  if (epi == 7 && n0 >= 2560) {   // transposed V store (block-uniform)
#pragma unroll
    for (int i = 0; i < 4; ++i)
#pragma unroll
      for (int j = 0; j < 4; ++j) {
        const int row = m0 + wr + i * 16 + quad * 4;
        const int col = n0 + wc + j * 16 + l16 - 2560;
        ushort4 o;
        o.x = f2b(acc[i][j][0]); o.y = f2b(acc[i][j][1]);
        o.z = f2b(acc[i][j][2]); o.w = f2b(acc[i][j][3]);
        *(ushort4*)(Cb3 + (size_t)col * Tld + row) = o;
      }
    return;
  }

#pragma unroll
  for (int i = 0; i < 4; ++i)
#pragma unroll
    for (int j = 0; j < 4; ++j) {
      const int rowb = m0 + wr + i * 16 + quad * 4;
      const int col = n0 + wc + j * 16 + l16;
      float invf = 0.f, sgn = 0.f;
      if (epi == 7) {
        const int ip = (col & 63) >> 1;
        invf = __expf(-(float)ip * 0.28782313662f); // 10000^(-ip/32)
        sgn = (col & 1) ? 1.f : -1.f;
      }
#pragma unroll
      for (int r = 0; r < 4; ++r) {
        const size_t idx = (size_t)(rowb + r) * N + col;
        const float v = acc[i][j][r];
        const float p = __shfl_xor(v, 1, 64);
        if (epi == 1) {
          Cf[idx] = v + b2f(add1b[idx]);
        } else if (epi == 3) {
          const float gt = b2f(add1b[idx]);
          Cb[idx] = f2b(gt / (1.f + __expf(-gt)) * v);
        } else if (epi == 4) {
          Cb[idx] = f2b(v);
        } else if (epi == 8) {
          atomicAdd(&Cf[idx], v);
        } else {  // 7: rope -> q or k (block-uniform region)
          float sn, cs;
          __sincosf((float)(rowb + r) * invf, &sn, &cs);
          const unsigned short o = f2b(v * cs + sgn * p * sn);
          if (col < 2048)
            Cb[(size_t)(rowb + r) * 2048 + col] = o;
          else
            Cb2[(size_t)(rowb + r) * 512 + col - 2048] = o;
        }
      }
    }
}

// ---------------------------------------------------------------------------
// Flash attention, transpose-free.  Block = 4 waves per (head, 16-q tile);
// wave w does 128-key chunks jt = w, w+4, ...  S^T = K.Q^T so the per-lane
// layout is S^T[key=quad*4+r][q=l16]; softmax is in-lane over 32 regs + 2
// shfl_xor (16,32); P^T is already the 16x16x16 B-frag (k=quad*4+j) so PV
// (O^T = V^T.P^T) runs from registers — no LDS, no fence in the loop.
// Q prescaled by 0.125 (exact).  LDS only for the 4-way merge at the end.
// ---------------------------------------------------------------------------
#define SLICE 4352
__global__ __launch_bounds__(256) void flash_attn(
    const unsigned short* __restrict__ Qb, const unsigned short* __restrict__ Kb,
    const unsigned short* __restrict__ Vt, unsigned short* __restrict__ Y,
    int T) {
  __shared__ char shmem[4 * SLICE];

  const int tid = threadIdx.x;
  const int wave = tid >> 6, lane = tid & 63;
  const int quad = lane >> 4, l16 = lane & 15;
  const int h = blockIdx.y;
  const int qt = gridDim.x - 1 - blockIdx.x;   // longest-job-first
  const int kvh = h >> 2;
  const int qbase = qt * 16;
  const int qabs = qbase + l16;

  // Q B-frags (n=q=l16, k=quad*8+j), prescaled by 1/8 (exact: exponent shift).
  short8 bQ[2];
#pragma unroll
  for (int c = 0; c < 2; ++c) {
    short8 q = *(const short8*)(Qb + (size_t)(qbase + l16) * 2048 + h * 64 +
                                c * 32 + quad * 8);
#pragma unroll
    for (int j = 0; j < 8; ++j)
      q[j] = (short)f2b(b2f((unsigned short)q[j]) * 0.125f);
    bQ[c] = q;
  }

  float m_i = -1e30f, l_i = 0.f;      // per-lane state for q = l16
  f32x4 Oacc[4] = {};                 // O^T[d=c*16+quad*4+r][q=l16]

  const int nchunk = (qbase + 16 + 127) >> 7;   // keys 0 .. qbase+15

  for (int jt = wave; jt < nchunk; jt += 4) {
    const int k0 = jt << 7;
    // ---- S^T = K.Q^T : 8 x 16-key subtiles, K-dim 64.
    f32x4 S[8];
#pragma unroll
    for (int s = 0; s < 8; ++s) {
      const size_t kr = (size_t)(k0 + s * 16 + l16) * 512 + kvh * 64;
      const short8 aK0 = *(const short8*)(Kb + kr + quad * 8);
      const short8 aK1 = *(const short8*)(Kb + kr + 32 + quad * 8);
      f32x4 z = {};
      z = __builtin_amdgcn_mfma_f32_16x16x32_bf16(aK0, bQ[0], z, 0, 0, 0);
      z = __builtin_amdgcn_mfma_f32_16x16x32_bf16(aK1, bQ[1], z, 0, 0, 0);
      S[s] = z;   // S[s][r] = S^T[k0+s*16+quad*4+r][qabs] (already scaled)
    }
    // ---- causal mask + max (in-lane 32 values, then xor 16, 32).
    float mx = -3e38f;
#pragma unroll
    for (int s = 0; s < 8; ++s)
#pragma unroll
      for (int r = 0; r < 4; ++r) {
        const int key = k0 + s * 16 + quad * 4 + r;
        float v = S[s][r];
        if (key > qabs) v = -3e38f;
        S[s][r] = v;
        mx = fmaxf(mx, v);
      }
    mx = fmaxf(mx, __shfl_xor(mx, 16, 64));
    mx = fmaxf(mx, __shfl_xor(mx, 32, 64));

    const float mn = fmaxf(m_i, mx);
    const float alpha = __expf(m_i - mn);
    m_i = mn;
    float rsum = 0.f;
    s4b bP[8];
#pragma unroll
    for (int s = 0; s < 8; ++s) {
      s4b pb;
#pragma unroll
      for (int r = 0; r < 4; ++r) {
        const float p = __expf(S[s][r] - mn);
        rsum += p;
        pb[r] = (short)f2b(p);
      }
      bP[s] = pb;   // B-frag of P^T: n=q=l16, k=quad*4+r
    }
    rsum += __shfl_xor(rsum, 16, 64);
    rsum += __shfl_xor(rsum, 32, 64);
    l_i = l_i * alpha + rsum;

    // ---- rescale O, then PV: O^T += V^T . P^T (16x16x16, K=16/subtile).
#pragma unroll
    for (int c = 0; c < 4; ++c)
#pragma unroll
      for (int r = 0; r < 4; ++r) Oacc[c][r] *= alpha;
#pragma unroll
    for (int c = 0; c < 4; ++c) {
      const size_t vr = (size_t)(kvh * 64 + c * 16 + l16) * T + k0;
#pragma unroll
      for (int s = 0; s < 8; ++s) {
        const s4b aV = *(const s4b*)(Vt + vr + s * 16 + quad * 4);
        Oacc[c] = __builtin_amdgcn_mfma_f32_16x16x16bf16_1k(aV, bP[s],
                                                            Oacc[c], 0, 0, 0);
      }
    }
  }

  // ---- merge the 4 per-wave partials.
  float* OWw = (float*)(shmem + wave * SLICE);   // [c][drow 16][q 16]
  float* mw  = (float*)(shmem + wave * SLICE + 4096);
  float* lw  = (float*)(shmem + wave * SLICE + 4160);
#pragma unroll
  for (int c = 0; c < 4; ++c)
#pragma unroll
    for (int r = 0; r < 4; ++r)
      OWw[c * 256 + (quad * 4 + r) * 16 + l16] = Oacc[c][r];
  if (quad == 0) { mw[l16] = m_i; lw[l16] = l_i; }
  __syncthreads();

  const int c = wave;   // this wave merges d-chunk c
  float M = -3e38f;
#pragma unroll
  for (int w2 = 0; w2 < 4; ++w2)
    M = fmaxf(M, ((const float*)(shmem + w2 * SLICE + 4096))[l16]);
  float den = 0.f, sc[4];
#pragma unroll
  for (int w2 = 0; w2 < 4; ++w2) {
    const float mv = ((const float*)(shmem + w2 * SLICE + 4096))[l16];
    const float lv = ((const float*)(shmem + w2 * SLICE + 4160))[l16];
    sc[w2] = __expf(mv - M);
    den += lv * sc[w2];
  }
  const float inv = 1.f / den;
  ushort4 o;
#pragma unroll
  for (int r = 0; r < 4; ++r) {
    float num = 0.f;
#pragma unroll
    for (int w2 = 0; w2 < 4; ++w2)
      num += ((const float*)(shmem + w2 * SLICE))[c * 256 +
                                                  (quad * 4 + r) * 16 + l16] *
             sc[w2];
    ((unsigned short*)&o)[r] = f2b(num * inv);
  }
  *(ushort4*)(Y + (size_t)(qbase + l16) * 2048 + h * 64 + c * 16 + quad * 4) = o;
}

// ---------------------------------------------------------------------------
extern "C" void kernel_launch(void* const* d_in, const int* in_sizes, int n_in,
                              void* d_out, int out_size, void* d_ws,
                              size_t ws_size, hipStream_t stream) {
  const float* x  = (const float*)d_in[0];
  const float* g1 = (const float*)d_in[1];
  const float* wq = (const float*)d_in[2];
  const float* wk = (const float*)d_in[3];
  const float* wv = (const float*)d_in[4];
  const float* wo = (const float*)d_in[5];
  const float* g2 = (const float*)d_in[6];
  const float* wg = (const float*)d_in[7];
  const float* wu = (const float*)d_in[8];
  const float* wd = (const float*)d_in[9];
  float* out = (float*)d_out;

  const int T = 2048, Dm = 2048, FF = 8192;
  char* ws = (char*)d_ws;
  const size_t MB = (size_t)1 << 20;

  unsigned short* wq_t = (unsigned short*)(ws + 0 * MB);    // 8 MB  } contig
  unsigned short* wk_t = (unsigned short*)(ws + 8 * MB);    // 2 MB  } rows
  unsigned short* wv_t = (unsigned short*)(ws + 10 * MB);   // 2 MB  } 0..3071
  unsigned short* wo_t = (unsigned short*)(ws + 12 * MB);   // 8 MB
  unsigned short* wg_t = (unsigned short*)(ws + 20 * MB);   // 32 MB
  unsigned short* wu_t = (unsigned short*)(ws + 52 * MB);   // 32 MB
  unsigned short* h1_b = (unsigned short*)(ws + 84 * MB);   // 8 MB
  unsigned short* h2_b = (unsigned short*)(ws + 92 * MB);   // 8 MB
  float*          x2_f = (float*)(ws + 100 * MB);           // 16 MB (dies early)
  unsigned short* gate = (unsigned short*)(ws + 100 * MB);  // 32 MB (in-place)
  unsigned short* q_b  = (unsigned short*)(ws + 132 * MB);  // 8 MB
  unsigned short* k_b  = (unsigned short*)(ws + 140 * MB);  // 2 MB
  unsigned short* vt_b = (unsigned short*)(ws + 142 * MB);  // 2 MB
  unsigned short* y_b  = (unsigned short*)(ws + 144 * MB);  // 8 MB
  unsigned short* wd_t = (unsigned short*)(ws + 132 * MB);  // 32 MB (after attn)

  // 1. Weight cast+transpose (wd deferred until attn scratch is dead).
  transpose_cast<<<dim3(64, 64), 256, 0, stream>>>(wq, wq_t, Dm, Dm);
  transpose_cast<<<dim3(16, 64), 256, 0, stream>>>(wk, wk_t, Dm, 512);
  transpose_cast<<<dim3(16, 64), 256, 0, stream>>>(wv, wv_t, Dm, 512);
  transpose_cast<<<dim3(64, 64), 256, 0, stream>>>(wo, wo_t, Dm, Dm);
  transpose_cast<<<dim3(256, 64), 256, 0, stream>>>(wg, wg_t, Dm, FF);
  transpose_cast<<<dim3(256, 64), 256, 0, stream>>>(wu, wu_t, Dm, FF);

  // 2. h1 = rms(x0)
  rmsnorm<<<T, 256, 0, stream>>>(x, g1, h1_b);

  // 3. Fused QKV projection (N=3072): rope q -> q_b, rope k -> k_b,
  //    transposed v -> vt_b.
  gemm_bt<<<dim3(24, 16), 256, 0, stream>>>(h1_b, wq_t, nullptr, q_b, nullptr,
                                            nullptr, 3072, Dm, Dm, 7, T, k_b,
                                            vt_b);

  // 4. Attention (4 waves/block, key-split, transpose-free PV).
  flash_attn<<<dim3(T / 16, 32), 256, 0, stream>>>(q_b, k_b, vt_b, y_b, T);

  // 5. x2 = h1 + y @ wo  (epi 1).
  gemm_bt<<<dim3(16, 16), 256, 0, stream>>>(y_b, wo_t, x2_f, nullptr, h1_b,
                                            nullptr, Dm, Dm, Dm, 1, 0, nullptr,
                                            nullptr);

  // 6. wd transpose into the now-dead attention scratch.
  transpose_cast<<<dim3(64, 256), 256, 0, stream>>>(wd, wd_t, FF, Dm);

  // 7. h2 = rms(x2)
  rmsnorm<<<T, 256, 0, stream>>>(x2_f, g2, h2_b);

  // 8. MLP: gate (epi 4), then up fused with silu in-place (epi 3).
  gemm_bt<<<dim3(64, 16), 256, 0, stream>>>(h2_b, wg_t, nullptr, gate, nullptr,
                                            nullptr, FF, Dm, Dm, 4, 0, nullptr,
                                            nullptr);
  gemm_bt<<<dim3(64, 16), 256, 0, stream>>>(h2_b, wu_t, nullptr, gate, gate,
                                            nullptr, FF, Dm, Dm, 3, 0, nullptr,
                                            nullptr);

  // 9. out = h2 + x0 (pre-fill), then split-K x4 down-proj atomicAdd.
  add_res<<<(T * Dm / 4) / 256, 256, 0, stream>>>(h2_b, x, out);
  gemm_bt<<<dim3(16, 16, 4), 256, 0, stream>>>(gate, wd_t, out, nullptr,
                                               nullptr, nullptr, Dm, FF,
                                               FF / 4, 8, 0, nullptr, nullptr);
}